// Round 9
// baseline (993.263 us; speedup 1.0000x reference)
//
#include <hip/hip_runtime.h>

#define E_TOTAL 50000
#define NTILES  3125      // E_TOTAL / 16, exact

typedef float f4  __attribute__((ext_vector_type(4)));
typedef short s8v __attribute__((ext_vector_type(8)));   // 8 bf16 bit-patterns (4 VGPRs)
typedef short s4v __attribute__((ext_vector_type(4)));   // 4 bf16 bit-patterns (2 VGPRs)

__device__ __forceinline__ short f2bf(float x){
  unsigned u = __builtin_bit_cast(unsigned, x);
  u += 0x7fffu + ((u >> 16) & 1u);           // RNE
  return (short)(u >> 16);
}
__device__ __forceinline__ float bf2f(short s){
  unsigned u = ((unsigned)(unsigned short)s) << 16;
  return __builtin_bit_cast(float, u);
}
__device__ __forceinline__ float sigm(float x){ return 1.f/(1.f + __expf(-x)); }

__device__ __forceinline__ s8v load_bfrag(const float* p){
  f4 a = *(const f4*)p;
  f4 b = *(const f4*)(p + 4);
  s8v r;
  r[0]=f2bf(a[0]); r[1]=f2bf(a[1]); r[2]=f2bf(a[2]); r[3]=f2bf(a[3]);
  r[4]=f2bf(b[0]); r[5]=f2bf(b[1]); r[6]=f2bf(b[2]); r[7]=f2bf(b[3]);
  return r;
}

// D[128 features x 16 edges] += A(direct from global/L2) @ B.
// Per k-group: 8 coalesced 16B loads (wave reads 1KB contiguous), then 8
// independent MFMAs (different accumulators). No LDS, no barriers.
__device__ __forceinline__ void mm8d(f4* acc, const s8v* B, const s8v* __restrict__ A, int lane){
  #pragma unroll
  for (int kk = 0; kk < 4; ++kk){
    s8v a[8];
    #pragma unroll
    for (int mb = 0; mb < 8; ++mb) a[mb] = A[(mb*4 + kk)*64 + lane];
    #pragma unroll
    for (int mb = 0; mb < 8; ++mb)
      acc[mb] = __builtin_amdgcn_mfma_f32_16x16x32_bf16(a[mb], B[kk], acc[mb], 0, 0, 0);
  }
}

// ---------------------------------------------------------------------------
// Precompute: 14 fragment-ready bf16 A-matrices (A[m][k] = W[k][m], optionally
// W = X@Y fused product), packed so lane reads 16B contiguous per (mblk,kk).
//   mi 0 WqT(nat) | 1 GKT=Wk@Wk1a | 2 GMT=Wv@Wm1a | 3 GKaT=We@Wk1c | 4 GMaT=We@Wm1c
//   mi 5 Wk2T(dlay) | 6 Wm2T(dlay) | 7 WcT(dlay) | 8..10 GKeT[t] | 11..13 GMeT[t]
// ---------------------------------------------------------------------------
__global__ __launch_bounds__(256) void pack_weights(
    const float* __restrict__ Wq, const float* __restrict__ Wk, const float* __restrict__ Wv,
    const float* __restrict__ Wke, const float* __restrict__ Wve, const float* __restrict__ We,
    const float* __restrict__ Wc, const float* __restrict__ Wk1, const float* __restrict__ Wk2,
    const float* __restrict__ Wm1, const float* __restrict__ Wm2,
    short* __restrict__ wsm)
{
  int mi   = blockIdx.x >> 6;
  int elem = ((blockIdx.x & 63) << 8) + threadIdx.x;   // 0..16383
  int p  = elem & 7;
  int l  = (elem >> 3) & 63;
  int kk = (elem >> 9) & 3;
  int mb = elem >> 11;
  int gg = l >> 4;
  int m  = mb*16 + (l & 15);
  bool dlay = (mi == 5) || (mi == 6) || (mi == 7);
  int k = dlay ? (kk*32 + ((p < 4) ? (gg*4 + p) : (16 + gg*4 + (p - 4))))
               : (kk*32 + gg*8 + p);

  const float* X = nullptr; const float* Y = nullptr; const float* W = nullptr;
  switch (mi){
    case 0: W = Wq; break;
    case 1: X = Wk; Y = Wk1;            break;
    case 2: X = Wv; Y = Wm1;            break;
    case 3: X = We; Y = Wk1 + 256*128;  break;
    case 4: X = We; Y = Wm1 + 256*128;  break;
    case 5: W = Wk2; break;
    case 6: W = Wm2; break;
    case 7: W = Wc;  break;
    default:
      if (mi < 11){ X = Wke + (mi-8)*16384;  Y = Wk1 + 128*128; }
      else        { X = Wve + (mi-11)*16384; Y = Wm1 + 128*128; }
  }
  float v;
  if (W){
    v = W[k*128 + m];
  } else {
    v = 0.f;
    for (int j = 0; j < 128; ++j) v += X[k*128 + j] * Y[j*128 + m];
  }
  wsm[(size_t)mi*16384 + elem] = f2bf(v);
}

// biasK[t] = bk@Wk1a + bke[t]@Wk1b + bk1 ; biasM[t] = bv@Wm1a + bve[t]@Wm1b + bm1
__global__ __launch_bounds__(128) void make_biases(
    const float* __restrict__ bk,  const float* __restrict__ bke, const float* __restrict__ bk1,
    const float* __restrict__ bv,  const float* __restrict__ bve, const float* __restrict__ bm1,
    const float* __restrict__ Wk1, const float* __restrict__ Wm1,
    float* __restrict__ wsb)
{
  int b = blockIdx.x;          // 0..2 -> biasK[t], 3..5 -> biasM[t]
  int t = b % 3;
  bool isM = b >= 3;
  int o = threadIdx.x;
  const float* W  = isM ? Wm1 : Wk1;
  const float* b0 = isM ? bv  : bk;
  const float* be = (isM ? bve : bke) + t*128;
  const float* b1 = isM ? bm1 : bk1;
  float v = b1[o];
  for (int j = 0; j < 128; ++j)
    v += b0[j]*W[j*128 + o] + be[j]*W[(128 + j)*128 + o];
  wsb[b*128 + o] = v;
}

// ---------------------------------------------------------------------------
// Main fused kernel: barrier-free, LDS-free. One wave = 16 edges, fully
// independent. All 22 GEMMs read A-fragments directly from the packed
// workspace (L2-resident, 448KB working set); latency hidden by wave-level
// parallelism (no convoy, no vmcnt(0) drains).
// D[m=feature][n=edge]; lane holds edge (lane&15), features mb*16+(lane>>4)*4+r.
// ---------------------------------------------------------------------------
__global__ __launch_bounds__(256) void edge_main(
    const float* __restrict__ edge, const float* __restrict__ nlen, const float* __restrict__ nang,
    const float* __restrict__ bq,   const float* __restrict__ bk2,  const float* __restrict__ bm2,
    const float* __restrict__ bc,
    const float* __restrict__ g_att, const float* __restrict__ b_att,
    const float* __restrict__ g_bn,  const float* __restrict__ b_bn,
    const short* __restrict__ wsm,  const float* __restrict__ wsb,
    float* __restrict__ out)
{
  const int lane = threadIdx.x & 63;
  const int wid  = threadIdx.x >> 6;
  int tile = blockIdx.x*4 + wid;
  if (tile > NTILES-1) tile = NTILES-1;   // tail waves redo last tile (benign, no sync)
  const int g  = lane >> 4;
  const int er = lane & 15;
  const size_t e = (size_t)tile*16 + er;
  const float* erow = edge + e*128;

  const s8v* A_q   = (const s8v*)(wsm + (size_t) 0*16384);
  const s8v* A_gk  = (const s8v*)(wsm + (size_t) 1*16384);
  const s8v* A_gm  = (const s8v*)(wsm + (size_t) 2*16384);
  const s8v* A_gka = (const s8v*)(wsm + (size_t) 3*16384);
  const s8v* A_gma = (const s8v*)(wsm + (size_t) 4*16384);
  const s8v* A_wk2 = (const s8v*)(wsm + (size_t) 5*16384);
  const s8v* A_wm2 = (const s8v*)(wsm + (size_t) 6*16384);
  const s8v* A_wc  = (const s8v*)(wsm + (size_t) 7*16384);

  // ---- input fragments (HBM; issued first, latency covered by first GEMMs) ----
  s8v BE[4], BL[4], BA[4];
  #pragma unroll
  for (int kk = 0; kk < 4; ++kk) BE[kk] = load_bfrag(erow + kk*32 + g*8);
  {
    const float* lrow = nlen + e*3*128;
    const float* arow = nang + e*3*128;
    #pragma unroll
    for (int kk = 0; kk < 4; ++kk){
      BL[kk] = load_bfrag(lrow + kk*32 + g*8);
      BA[kk] = load_bfrag(arow + kk*32 + g*8);
    }
  }

  f4 acc[8], gm[8];
  s4v qb[8], ekb[8], emb[8], gateb[8];
  s8v S[4];

  // ---- q = Wq^T @ edge^T + bq ----
  #pragma unroll
  for (int mb = 0; mb < 8; ++mb) acc[mb] = *(const f4*)(bq + mb*16 + g*4);
  mm8d(acc, BE, A_q, lane);
  #pragma unroll
  for (int mb = 0; mb < 8; ++mb){
    s4v t4; t4[0]=f2bf(acc[mb][0]); t4[1]=f2bf(acc[mb][1]); t4[2]=f2bf(acc[mb][2]); t4[3]=f2bf(acc[mb][3]);
    qb[mb] = t4;
  }
  // ---- ek = GK^T @ edge^T ----
  #pragma unroll
  for (int mb = 0; mb < 8; ++mb){ f4 z = {0.f,0.f,0.f,0.f}; acc[mb] = z; }
  mm8d(acc, BE, A_gk, lane);
  #pragma unroll
  for (int mb = 0; mb < 8; ++mb){
    s4v t4; t4[0]=f2bf(acc[mb][0]); t4[1]=f2bf(acc[mb][1]); t4[2]=f2bf(acc[mb][2]); t4[3]=f2bf(acc[mb][3]);
    ekb[mb] = t4;
  }
  // ---- em = GM^T @ edge^T ----
  #pragma unroll
  for (int mb = 0; mb < 8; ++mb){ f4 z = {0.f,0.f,0.f,0.f}; acc[mb] = z; }
  mm8d(acc, BE, A_gm, lane);
  #pragma unroll
  for (int mb = 0; mb < 8; ++mb){
    s4v t4; t4[0]=f2bf(acc[mb][0]); t4[1]=f2bf(acc[mb][1]); t4[2]=f2bf(acc[mb][2]); t4[3]=f2bf(acc[mb][3]);
    emb[mb] = t4;
  }
  #pragma unroll
  for (int mb = 0; mb < 8; ++mb){ f4 z = {0.f,0.f,0.f,0.f}; gm[mb] = z; }

  #pragma unroll 1
  for (int t = 0; t < 3; ++t){
    const s8v* A_gke = (const s8v*)(wsm + (size_t)(8 + t)*16384);
    const s8v* A_gme = (const s8v*)(wsm + (size_t)(11 + t)*16384);

    // pA: h = biasK[t] + ekb ; += BL @ GKe[t]
    #pragma unroll
    for (int mb = 0; mb < 8; ++mb){
      f4 b = *(const f4*)(wsb + t*128 + mb*16 + g*4);
      #pragma unroll
      for (int r = 0; r < 4; ++r) b[r] += bf2f(ekb[mb][r]);
      acc[mb] = b;
    }
    mm8d(acc, BL, A_gke, lane);

    // pB: h += BA @ GKa ; silu -> S
    mm8d(acc, BA, A_gka, lane);
    #pragma unroll
    for (int kk = 0; kk < 4; ++kk){
      #pragma unroll
      for (int p = 0; p < 4; ++p){
        float x0 = acc[2*kk][p];   S[kk][p]   = f2bf(x0 * sigm(x0));
        float x1 = acc[2*kk+1][p]; S[kk][4+p] = f2bf(x1 * sigm(x1));
      }
    }

    // pC: alpha = q .* (S@Wk2 + bk2)/sqrt(C) ; LN ; gate
    #pragma unroll
    for (int mb = 0; mb < 8; ++mb) acc[mb] = *(const f4*)(bk2 + mb*16 + g*4);
    mm8d(acc, S, A_wk2, lane);
    {
      float sm = 0.f, ssq = 0.f;
      #pragma unroll
      for (int mb = 0; mb < 8; ++mb){
        #pragma unroll
        for (int r = 0; r < 4; ++r){
          float a = bf2f(qb[mb][r]) * acc[mb][r] * 0.08838834764831845f;
          acc[mb][r] = a; sm += a; ssq += a*a;
        }
      }
      sm  += __shfl_xor(sm, 16);  sm  += __shfl_xor(sm, 32);
      ssq += __shfl_xor(ssq, 16); ssq += __shfl_xor(ssq, 32);
      float mean = sm * (1.f/128.f);
      float rstd = rsqrtf(ssq * (1.f/128.f) - mean*mean + 1e-5f);
      #pragma unroll
      for (int mb = 0; mb < 8; ++mb){
        f4 ga = *(const f4*)(g_att + mb*16 + g*4);
        f4 bb = *(const f4*)(b_att + mb*16 + g*4);
        s4v t4;
        #pragma unroll
        for (int r = 0; r < 4; ++r)
          t4[r] = f2bf(sigm((acc[mb][r] - mean)*rstd*ga[r] + bb[r]));
        gateb[mb] = t4;
      }
    }

    // pD: h = biasM[t] + emb ; += BL @ GMe[t] ; BL dead -> reload BL(t+1)
    #pragma unroll
    for (int mb = 0; mb < 8; ++mb){
      f4 b = *(const f4*)(wsb + 384 + t*128 + mb*16 + g*4);
      #pragma unroll
      for (int r = 0; r < 4; ++r) b[r] += bf2f(emb[mb][r]);
      acc[mb] = b;
    }
    mm8d(acc, BL, A_gme, lane);
    if (t < 2){
      const float* lrow = nlen + (e*3 + t + 1)*128;
      #pragma unroll
      for (int kk = 0; kk < 4; ++kk) BL[kk] = load_bfrag(lrow + kk*32 + g*8);
    }

    // pE: h += BA @ GMa ; silu -> S ; BA dead -> reload BA(t+1)
    mm8d(acc, BA, A_gma, lane);
    #pragma unroll
    for (int kk = 0; kk < 4; ++kk){
      #pragma unroll
      for (int p = 0; p < 4; ++p){
        float x0 = acc[2*kk][p];   S[kk][p]   = f2bf(x0 * sigm(x0));
        float x1 = acc[2*kk+1][p]; S[kk][4+p] = f2bf(x1 * sigm(x1));
      }
    }
    if (t < 2){
      const float* arow = nang + (e*3 + t + 1)*128;
      #pragma unroll
      for (int kk = 0; kk < 4; ++kk) BA[kk] = load_bfrag(arow + kk*32 + g*8);
    }

    // pF: ma = S@Wm2 + bm2 ; gm += gate .* ma
    #pragma unroll
    for (int mb = 0; mb < 8; ++mb) acc[mb] = *(const f4*)(bm2 + mb*16 + g*4);
    mm8d(acc, S, A_wm2, lane);
    #pragma unroll
    for (int mb = 0; mb < 8; ++mb){
      #pragma unroll
      for (int r = 0; r < 4; ++r) gm[mb][r] += acc[mb][r] * bf2f(gateb[mb][r]);
    }
  }

  // ---- epilogue: o = gm@Wc + 3bc ; LN ; softplus(edge + .) ; store ----
  s8v GF[4];
  #pragma unroll
  for (int kk = 0; kk < 4; ++kk){
    #pragma unroll
    for (int p = 0; p < 4; ++p){
      GF[kk][p]   = f2bf(gm[2*kk][p]);
      GF[kk][4+p] = f2bf(gm[2*kk+1][p]);
    }
  }
  #pragma unroll
  for (int mb = 0; mb < 8; ++mb){
    f4 b = *(const f4*)(bc + mb*16 + g*4);
    #pragma unroll
    for (int r = 0; r < 4; ++r) b[r] *= 3.f;
    acc[mb] = b;
  }
  mm8d(acc, GF, A_wc, lane);

  float sm = 0.f, ssq = 0.f;
  #pragma unroll
  for (int mb = 0; mb < 8; ++mb){
    #pragma unroll
    for (int r = 0; r < 4; ++r){ sm += acc[mb][r]; ssq += acc[mb][r]*acc[mb][r]; }
  }
  sm  += __shfl_xor(sm, 16);  sm  += __shfl_xor(sm, 32);
  ssq += __shfl_xor(ssq, 16); ssq += __shfl_xor(ssq, 32);
  float mean = sm * (1.f/128.f);
  float rstd = rsqrtf(ssq * (1.f/128.f) - mean*mean + 1e-5f);

  #pragma unroll
  for (int mb = 0; mb < 8; ++mb){
    f4 ev  = *(const f4*)(erow + mb*16 + g*4);
    f4 gv  = *(const f4*)(g_bn + mb*16 + g*4);
    f4 bv2 = *(const f4*)(b_bn + mb*16 + g*4);
    f4 o;
    #pragma unroll
    for (int r = 0; r < 4; ++r){
      float x = ev[r] + (acc[mb][r] - mean)*rstd*gv[r] + bv2[r];
      o[r] = (x > 20.f) ? x : log1pf(__expf(x));
    }
    *(f4*)(out + e*128 + mb*16 + g*4) = o;
  }
}

extern "C" void kernel_launch(void* const* d_in, const int* in_sizes, int n_in,
                              void* d_out, int out_size, void* d_ws, size_t ws_size,
                              hipStream_t stream)
{
  const float* edge = (const float*)d_in[0];
  const float* nlen = (const float*)d_in[1];
  const float* nang = (const float*)d_in[2];
  const float* Wq  = (const float*)d_in[3];
  const float* bq  = (const float*)d_in[4];
  const float* Wk  = (const float*)d_in[5];
  const float* bk  = (const float*)d_in[6];
  const float* Wv  = (const float*)d_in[7];
  const float* bv  = (const float*)d_in[8];
  const float* Wke = (const float*)d_in[9];
  const float* bke = (const float*)d_in[10];
  const float* Wve = (const float*)d_in[11];
  const float* bve = (const float*)d_in[12];
  const float* We  = (const float*)d_in[13];
  const float* Wc  = (const float*)d_in[14];
  const float* bc  = (const float*)d_in[15];
  const float* Wk1 = (const float*)d_in[16];
  const float* bk1 = (const float*)d_in[17];
  const float* Wk2 = (const float*)d_in[18];
  const float* bk2 = (const float*)d_in[19];
  const float* Wm1 = (const float*)d_in[20];
  const float* bm1 = (const float*)d_in[21];
  const float* Wm2 = (const float*)d_in[22];
  const float* bm2 = (const float*)d_in[23];
  const float* g_att = (const float*)d_in[24];
  const float* b_att = (const float*)d_in[25];
  const float* g_bn  = (const float*)d_in[26];
  const float* b_bn  = (const float*)d_in[27];

  // ws layout: 14 packed bf16 matrices (16384 shorts each) + 6*128 f32 biases
  short* wsm = (short*)d_ws;
  float* wsb = (float*)((char*)d_ws + (size_t)14*16384*2);

  pack_weights<<<dim3(14*64), dim3(256), 0, stream>>>(
      Wq, Wk, Wv, Wke, Wve, We, Wc, Wk1, Wk2, Wm1, Wm2, wsm);
  make_biases<<<dim3(6), dim3(128), 0, stream>>>(
      bk, bke, bk1, bv, bve, bm1, Wk1, Wm1, wsb);
  edge_main<<<dim3((NTILES + 3)/4), dim3(256), 0, stream>>>(
      edge, nlen, nang, bq, bk2, bm2, bc, g_att, b_att, g_bn, b_bn,
      wsm, wsb, (float*)d_out);
}

// Round 10
// 309.220 us; speedup vs baseline: 3.2122x; 3.2122x over previous
//
#include <hip/hip_runtime.h>

#define E_TOTAL 50000
#define NTILES  3125      // E_TOTAL / 16, exact
#define NBLK    1563      // 2 tiles (32 edges) per block

typedef float f4  __attribute__((ext_vector_type(4)));
typedef short s8v __attribute__((ext_vector_type(8)));   // 8 bf16 bit-patterns (4 VGPRs)
typedef short s4v __attribute__((ext_vector_type(4)));   // 4 bf16 bit-patterns (2 VGPRs)

typedef __attribute__((address_space(3))) unsigned lds_u32;
typedef __attribute__((address_space(1))) const unsigned g_u32;

__device__ __forceinline__ short f2bf(float x){
  unsigned u = __builtin_bit_cast(unsigned, x);
  u += 0x7fffu + ((u >> 16) & 1u);           // RNE
  return (short)(u >> 16);
}
__device__ __forceinline__ float bf2f(short s){
  unsigned u = ((unsigned)(unsigned short)s) << 16;
  return __builtin_bit_cast(float, u);
}
__device__ __forceinline__ float sigm(float x){ return 1.f/(1.f + __expf(-x)); }

__device__ __forceinline__ s8v load_bfrag(const float* p){
  f4 a = *(const f4*)p;
  f4 b = *(const f4*)(p + 4);
  s8v r;
  r[0]=f2bf(a[0]); r[1]=f2bf(a[1]); r[2]=f2bf(a[2]); r[3]=f2bf(a[3]);
  r[4]=f2bf(b[0]); r[5]=f2bf(b[1]); r[6]=f2bf(b[2]); r[7]=f2bf(b[3]);
  return r;
}

// Half-matrix GEMM: D[64 feats x 16 edges] += A(half of staged 32KB) @ B(regs)
__device__ __forceinline__ void mm4(f4* a4, const s8v* B, const s8v* A, int lane){
  #pragma unroll
  for (int mb = 0; mb < 4; ++mb){
    #pragma unroll
    for (int kk = 0; kk < 4; ++kk){
      s8v af = A[(mb*4 + kk)*64 + lane];
      a4[mb] = __builtin_amdgcn_mfma_f32_16x16x32_bf16(af, B[kk], a4[mb], 0, 0, 0);
    }
  }
}

// B-operand fragment from tile scratch (16B chunks swizzled: c ^= er&15)
__device__ __forceinline__ s8v get_frag(const short* SC, int kk, int er, int g){
  int c = (kk*4 + g) ^ (er & 15);
  return *(const s8v*)(SC + er*128 + c*8);
}
// Half-matrix GEMM with B from scratch
__device__ __forceinline__ void mmS(f4* a4, const short* SC, const s8v* A,
                                    int lane, int er, int g){
  #pragma unroll
  for (int kk = 0; kk < 4; ++kk){
    s8v b = get_frag(SC, kk, er, g);
    #pragma unroll
    for (int mb = 0; mb < 4; ++mb){
      s8v af = A[(mb*4 + kk)*64 + lane];
      a4[mb] = __builtin_amdgcn_mfma_f32_16x16x32_bf16(af, b, a4[mb], 0, 0, 0);
    }
  }
}

// Write this wave's half of a 16x128 bf16 matrix into tile scratch (8B units,
// swizzled u' = parity | ((u>>1 ^ er)<<1) -> 16B-chunk swizzle c^=er&15).
__device__ __forceinline__ void put_half(short* SC, const f4* a, int half, int er, int g,
                                         bool dosilu){
  #pragma unroll
  for (int mb = 0; mb < 4; ++mb){
    int u  = half*16 + mb*4 + g;
    int up = (u & 1) | ((((u >> 1) ^ er) & 15) << 1);
    s4v t;
    #pragma unroll
    for (int r = 0; r < 4; ++r){
      float x = a[mb][r];
      t[r] = f2bf(dosilu ? x * sigm(x) : x);
    }
    *(s4v*)(SC + er*128 + up*4) = t;
  }
}

// Cooperative 32KB matrix stage for 256 threads: 8 iters x 16B/thread.
__device__ __forceinline__ void stage_mat(const short* __restrict__ src,
                                          short* dst, int wid, int lane){
  #pragma unroll
  for (int j = 0; j < 8; ++j){
    const short* gsrc = src + j*2048 + wid*512 + lane*8;
    short* ldst = dst + j*2048 + wid*512;                  // wave-uniform
    __builtin_amdgcn_global_load_lds((g_u32*)(const void*)gsrc, (lds_u32*)(void*)ldst, 16, 0, 0);
  }
}

// ---------------------------------------------------------------------------
// Precompute: 14 fragment-ready bf16 A-matrices, A[m][k] = W[k][m] (or fused
// product X@Y), packed so lane reads 16B contiguous per (mblk,kk); NATURAL
// k-order for all (the LDS scratch exchange supplies natural-order B-frags).
//   mi 0 WqT | 1 GKT=Wk@Wk1a | 2 GMT=Wv@Wm1a | 3 GKaT=We@Wk1c | 4 GMaT=We@Wm1c
//   mi 5 Wk2T | 6 Wm2T | 7 WcT | 8..10 GKeT[t] | 11..13 GMeT[t]
// ---------------------------------------------------------------------------
__global__ __launch_bounds__(256) void pack_weights(
    const float* __restrict__ Wq, const float* __restrict__ Wk, const float* __restrict__ Wv,
    const float* __restrict__ Wke, const float* __restrict__ Wve, const float* __restrict__ We,
    const float* __restrict__ Wc, const float* __restrict__ Wk1, const float* __restrict__ Wk2,
    const float* __restrict__ Wm1, const float* __restrict__ Wm2,
    short* __restrict__ wsm)
{
  int mi   = blockIdx.x >> 6;
  int elem = ((blockIdx.x & 63) << 8) + threadIdx.x;   // 0..16383
  int p  = elem & 7;
  int l  = (elem >> 3) & 63;
  int kk = (elem >> 9) & 3;
  int mb = elem >> 11;
  int gg = l >> 4;
  int m  = mb*16 + (l & 15);
  int k  = kk*32 + gg*8 + p;

  const float* X = nullptr; const float* Y = nullptr; const float* W = nullptr;
  switch (mi){
    case 0: W = Wq; break;
    case 1: X = Wk; Y = Wk1;            break;
    case 2: X = Wv; Y = Wm1;            break;
    case 3: X = We; Y = Wk1 + 256*128;  break;
    case 4: X = We; Y = Wm1 + 256*128;  break;
    case 5: W = Wk2; break;
    case 6: W = Wm2; break;
    case 7: W = Wc;  break;
    default:
      if (mi < 11){ X = Wke + (mi-8)*16384;  Y = Wk1 + 128*128; }
      else        { X = Wve + (mi-11)*16384; Y = Wm1 + 128*128; }
  }
  float v;
  if (W){
    v = W[k*128 + m];
  } else {
    v = 0.f;
    for (int j = 0; j < 128; ++j) v += X[k*128 + j] * Y[j*128 + m];
  }
  wsm[(size_t)mi*16384 + elem] = f2bf(v);
}

// biasK[t] = bk@Wk1a + bke[t]@Wk1b + bk1 ; biasM[t] = bv@Wm1a + bve[t]@Wm1b + bm1
__global__ __launch_bounds__(128) void make_biases(
    const float* __restrict__ bk,  const float* __restrict__ bke, const float* __restrict__ bk1,
    const float* __restrict__ bv,  const float* __restrict__ bve, const float* __restrict__ bm1,
    const float* __restrict__ Wk1, const float* __restrict__ Wm1,
    float* __restrict__ wsb)
{
  int b = blockIdx.x;          // 0..2 -> biasK[t], 3..5 -> biasM[t]
  int t = b % 3;
  bool isM = b >= 3;
  int o = threadIdx.x;
  const float* W  = isM ? Wm1 : Wk1;
  const float* b0 = isM ? bv  : bk;
  const float* be = (isM ? bve : bke) + t*128;
  const float* b1 = isM ? bm1 : bk1;
  float v = b1[o];
  for (int j = 0; j < 128; ++j)
    v += b0[j]*W[j*128 + o] + be[j]*W[(128 + j)*128 + o];
  wsb[b*128 + o] = v;
}

// ---------------------------------------------------------------------------
// Main fused kernel. 4 waves/block = 2 tiles x 2 feature-halves. Each wave
// computes 64 of 128 features for its 16 edges -> per-wave register state
// ~halved (goal: 2-3 waves/SIMD in the unified VGPR/AGPR file, vs 1 before).
// Cross-half exchange (silu'd h -> S, gm -> GF, LN sums) via 4KB/tile
// XOR-swizzled LDS scratch. 22-phase r2-style double-buffered weight stream.
// ---------------------------------------------------------------------------
__global__ __launch_bounds__(256) void edge_main(
    const float* __restrict__ edge, const float* __restrict__ nlen, const float* __restrict__ nang,
    const float* __restrict__ bq,   const float* __restrict__ bk2,  const float* __restrict__ bm2,
    const float* __restrict__ bc,
    const float* __restrict__ g_att, const float* __restrict__ b_att,
    const float* __restrict__ g_bn,  const float* __restrict__ b_bn,
    const short* __restrict__ wsm,  const float* __restrict__ wsb,
    float* __restrict__ out)
{
  __shared__ short smem[36864];   // B0 32KB | B1 32KB | scratch 2x4KB = 72KB
  __shared__ float lnb[128];      // [tile][half][er][{sum,ssq}]
  short* B0 = smem;
  short* B1 = smem + 16384;

  const int lane  = threadIdx.x & 63;
  const int wid   = threadIdx.x >> 6;
  const int half  = wid & 1;
  const int tilew = wid >> 1;
  int tile = blockIdx.x*2 + tilew;
  if (tile > NTILES-1) tile = NTILES-1;   // dup of last tile writes identical data
  const int g = lane >> 4, er = lane & 15;
  const size_t e = (size_t)tile*16 + er;
  const float* erow = edge + e*128;
  short* SC = smem + 32768 + tilew*2048;  // this tile's 4KB scratch
  float* LN = lnb + tilew*64;             // [half][er][2]
  const int hoff = half*1024;             // s8v offset of this wave's A-half
  const int ho64 = half*64;               // feature offset for params/IO

  // ---- prologue: stage Wq -> B0 ; edge fragments ----
  stage_mat(wsm + 0*16384, B0, wid, lane);
  s8v BE[4];
  #pragma unroll
  for (int kk = 0; kk < 4; ++kk) BE[kk] = load_bfrag(erow + kk*32 + g*8);

  f4 acc[4], gm[4];
  s4v qb[4], ekb[4], emb[4], gateb[4];
  s8v BL[4], BA[4];
  __syncthreads();

  // p0: Wq -> qb ; stage GK -> B1
  stage_mat(wsm + 1*16384, B1, wid, lane);
  #pragma unroll
  for (int mb = 0; mb < 4; ++mb) acc[mb] = *(const f4*)(bq + ho64 + mb*16 + g*4);
  mm4(acc, BE, (const s8v*)B0 + hoff, lane);
  #pragma unroll
  for (int mb = 0; mb < 4; ++mb){
    s4v t; t[0]=f2bf(acc[mb][0]); t[1]=f2bf(acc[mb][1]); t[2]=f2bf(acc[mb][2]); t[3]=f2bf(acc[mb][3]);
    qb[mb] = t;
  }
  __syncthreads();

  // p1: GK -> ekb ; stage GM -> B0
  stage_mat(wsm + 2*16384, B0, wid, lane);
  #pragma unroll
  for (int mb = 0; mb < 4; ++mb){ f4 z = {0.f,0.f,0.f,0.f}; acc[mb] = z; }
  mm4(acc, BE, (const s8v*)B1 + hoff, lane);
  #pragma unroll
  for (int mb = 0; mb < 4; ++mb){
    s4v t; t[0]=f2bf(acc[mb][0]); t[1]=f2bf(acc[mb][1]); t[2]=f2bf(acc[mb][2]); t[3]=f2bf(acc[mb][3]);
    ekb[mb] = t;
  }
  __syncthreads();

  // p2: GM -> emb ; stage GKe0 -> B1 ; load BL/BA(t=0)
  stage_mat(wsm + 8*16384, B1, wid, lane);
  #pragma unroll
  for (int mb = 0; mb < 4; ++mb){ f4 z = {0.f,0.f,0.f,0.f}; acc[mb] = z; }
  mm4(acc, BE, (const s8v*)B0 + hoff, lane);
  #pragma unroll
  for (int mb = 0; mb < 4; ++mb){
    s4v t; t[0]=f2bf(acc[mb][0]); t[1]=f2bf(acc[mb][1]); t[2]=f2bf(acc[mb][2]); t[3]=f2bf(acc[mb][3]);
    emb[mb] = t;
  }
  {
    const float* lrow = nlen + e*3*128;
    const float* arow = nang + e*3*128;
    #pragma unroll
    for (int kk = 0; kk < 4; ++kk){
      BL[kk] = load_bfrag(lrow + kk*32 + g*8);
      BA[kk] = load_bfrag(arow + kk*32 + g*8);
    }
  }
  #pragma unroll
  for (int mb = 0; mb < 4; ++mb){ f4 z = {0.f,0.f,0.f,0.f}; gm[mb] = z; }
  __syncthreads();

  #pragma unroll 1
  for (int t = 0; t < 3; ++t){
    // pA: GKe[t] from B1 (B=BL); acc = biasK[t] + ekb ; stage GKa -> B0
    stage_mat(wsm + 3*16384, B0, wid, lane);
    #pragma unroll
    for (int mb = 0; mb < 4; ++mb){
      f4 b = *(const f4*)(wsb + t*128 + ho64 + mb*16 + g*4);
      #pragma unroll
      for (int r = 0; r < 4; ++r) b[r] += bf2f(ekb[mb][r]);
      acc[mb] = b;
    }
    mm4(acc, BL, (const s8v*)B1 + hoff, lane);
    __syncthreads();

    // pB: GKa from B0 (B=BA) ; silu -> scratch ; stage Wk2 -> B1
    stage_mat(wsm + 5*16384, B1, wid, lane);
    mm4(acc, BA, (const s8v*)B0 + hoff, lane);
    put_half(SC, acc, half, er, g, true);
    __syncthreads();

    // pC: Wk2 from B1 (B=S scratch) -> k-half ; alpha ; LN (cross-wave) ;
    //     gate ; stage GMe[t] -> B0
    stage_mat(wsm + (size_t)(11+t)*16384, B0, wid, lane);
    #pragma unroll
    for (int mb = 0; mb < 4; ++mb) acc[mb] = *(const f4*)(bk2 + ho64 + mb*16 + g*4);
    mmS(acc, SC, (const s8v*)B1 + hoff, lane, er, g);
    {
      float sm = 0.f, ssq = 0.f;
      #pragma unroll
      for (int mb = 0; mb < 4; ++mb){
        #pragma unroll
        for (int r = 0; r < 4; ++r){
          float a = bf2f(qb[mb][r]) * acc[mb][r] * 0.08838834764831845f;
          acc[mb][r] = a; sm += a; ssq += a*a;
        }
      }
      sm  += __shfl_xor(sm, 16);  sm  += __shfl_xor(sm, 32);
      ssq += __shfl_xor(ssq, 16); ssq += __shfl_xor(ssq, 32);
      if (lane < 16){ LN[half*32 + lane*2] = sm; LN[half*32 + lane*2 + 1] = ssq; }
    }
    __syncthreads();
    {
      float s0 = LN[er*2]     + LN[32 + er*2];
      float q0 = LN[er*2 + 1] + LN[32 + er*2 + 1];
      float mean = s0 * (1.f/128.f);
      float rstd = rsqrtf(q0 * (1.f/128.f) - mean*mean + 1e-5f);
      #pragma unroll
      for (int mb = 0; mb < 4; ++mb){
        f4 ga = *(const f4*)(g_att + ho64 + mb*16 + g*4);
        f4 bb = *(const f4*)(b_att + ho64 + mb*16 + g*4);
        s4v t4;
        #pragma unroll
        for (int r = 0; r < 4; ++r)
          t4[r] = f2bf(sigm((acc[mb][r] - mean)*rstd*ga[r] + bb[r]));
        gateb[mb] = t4;
      }
    }
    __syncthreads();

    // pD: GMe[t] from B0 (B=BL); acc = biasM[t] + emb ; stage GMa -> B1 ;
    //     reload BL(t+1)
    stage_mat(wsm + 4*16384, B1, wid, lane);
    #pragma unroll
    for (int mb = 0; mb < 4; ++mb){
      f4 b = *(const f4*)(wsb + 384 + t*128 + ho64 + mb*16 + g*4);
      #pragma unroll
      for (int r = 0; r < 4; ++r) b[r] += bf2f(emb[mb][r]);
      acc[mb] = b;
    }
    mm4(acc, BL, (const s8v*)B0 + hoff, lane);
    if (t < 2){
      const float* lrow = nlen + (e*3 + t + 1)*128;
      #pragma unroll
      for (int kk = 0; kk < 4; ++kk) BL[kk] = load_bfrag(lrow + kk*32 + g*8);
    }
    __syncthreads();

    // pE: GMa from B1 (B=BA) ; silu -> scratch ; stage Wm2 -> B0 ; reload BA(t+1)
    stage_mat(wsm + 6*16384, B0, wid, lane);
    mm4(acc, BA, (const s8v*)B1 + hoff, lane);
    put_half(SC, acc, half, er, g, true);
    if (t < 2){
      const float* arow = nang + (e*3 + t + 1)*128;
      #pragma unroll
      for (int kk = 0; kk < 4; ++kk) BA[kk] = load_bfrag(arow + kk*32 + g*8);
    }
    __syncthreads();

    // pF: Wm2 from B0 (B=S scratch) -> ma ; gm += gate*ma ;
    //     stage next (GKe[t+1] or Wc) -> B1
    stage_mat(wsm + (size_t)(t < 2 ? 9 + t : 7)*16384, B1, wid, lane);
    #pragma unroll
    for (int mb = 0; mb < 4; ++mb) acc[mb] = *(const f4*)(bm2 + ho64 + mb*16 + g*4);
    mmS(acc, SC, (const s8v*)B0 + hoff, lane, er, g);
    #pragma unroll
    for (int mb = 0; mb < 4; ++mb){
      #pragma unroll
      for (int r = 0; r < 4; ++r) gm[mb][r] += acc[mb][r] * bf2f(gateb[mb][r]);
    }
    __syncthreads();
  }

  // pG: gm -> scratch (bf16 GF) ; Wc from B1 (B=GF) ; LN ; softplus ; store
  put_half(SC, gm, half, er, g, false);
  __syncthreads();
  #pragma unroll
  for (int mb = 0; mb < 4; ++mb){
    f4 b = *(const f4*)(bc + ho64 + mb*16 + g*4);
    #pragma unroll
    for (int r = 0; r < 4; ++r) b[r] *= 3.f;
    acc[mb] = b;
  }
  mmS(acc, SC, (const s8v*)B1 + hoff, lane, er, g);
  {
    float sm = 0.f, ssq = 0.f;
    #pragma unroll
    for (int mb = 0; mb < 4; ++mb){
      #pragma unroll
      for (int r = 0; r < 4; ++r){ sm += acc[mb][r]; ssq += acc[mb][r]*acc[mb][r]; }
    }
    sm  += __shfl_xor(sm, 16);  sm  += __shfl_xor(sm, 32);
    ssq += __shfl_xor(ssq, 16); ssq += __shfl_xor(ssq, 32);
    if (lane < 16){ LN[half*32 + lane*2] = sm; LN[half*32 + lane*2 + 1] = ssq; }
  }
  __syncthreads();
  {
    float s0 = LN[er*2]     + LN[32 + er*2];
    float q0 = LN[er*2 + 1] + LN[32 + er*2 + 1];
    float mean = s0 * (1.f/128.f);
    float rstd = rsqrtf(q0 * (1.f/128.f) - mean*mean + 1e-5f);
    #pragma unroll
    for (int mb = 0; mb < 4; ++mb){
      f4 ev  = *(const f4*)(erow + ho64 + mb*16 + g*4);
      f4 gv  = *(const f4*)(g_bn + ho64 + mb*16 + g*4);
      f4 bv2 = *(const f4*)(b_bn + ho64 + mb*16 + g*4);
      f4 o;
      #pragma unroll
      for (int r = 0; r < 4; ++r){
        float x = ev[r] + (acc[mb][r] - mean)*rstd*gv[r] + bv2[r];
        o[r] = (x > 20.f) ? x : log1pf(__expf(x));
      }
      *(f4*)(out + e*128 + ho64 + mb*16 + g*4) = o;
    }
  }
}

extern "C" void kernel_launch(void* const* d_in, const int* in_sizes, int n_in,
                              void* d_out, int out_size, void* d_ws, size_t ws_size,
                              hipStream_t stream)
{
  const float* edge = (const float*)d_in[0];
  const float* nlen = (const float*)d_in[1];
  const float* nang = (const float*)d_in[2];
  const float* Wq  = (const float*)d_in[3];
  const float* bq  = (const float*)d_in[4];
  const float* Wk  = (const float*)d_in[5];
  const float* bk  = (const float*)d_in[6];
  const float* Wv  = (const float*)d_in[7];
  const float* bv  = (const float*)d_in[8];
  const float* Wke = (const float*)d_in[9];
  const float* bke = (const float*)d_in[10];
  const float* Wve = (const float*)d_in[11];
  const float* bve = (const float*)d_in[12];
  const float* We  = (const float*)d_in[13];
  const float* Wc  = (const float*)d_in[14];
  const float* bc  = (const float*)d_in[15];
  const float* Wk1 = (const float*)d_in[16];
  const float* bk1 = (const float*)d_in[17];
  const float* Wk2 = (const float*)d_in[18];
  const float* bk2 = (const float*)d_in[19];
  const float* Wm1 = (const float*)d_in[20];
  const float* bm1 = (const float*)d_in[21];
  const float* Wm2 = (const float*)d_in[22];
  const float* bm2 = (const float*)d_in[23];
  const float* g_att = (const float*)d_in[24];
  const float* b_att = (const float*)d_in[25];
  const float* g_bn  = (const float*)d_in[26];
  const float* b_bn  = (const float*)d_in[27];

  // ws layout: 14 packed bf16 matrices (16384 shorts each) + 6*128 f32 biases
  short* wsm = (short*)d_ws;
  float* wsb = (float*)((char*)d_ws + (size_t)14*16384*2);

  pack_weights<<<dim3(14*64), dim3(256), 0, stream>>>(
      Wq, Wk, Wv, Wke, Wve, We, Wc, Wk1, Wk2, Wm1, Wm2, wsm);
  make_biases<<<dim3(6), dim3(128), 0, stream>>>(
      bk, bke, bk1, bv, bve, bm1, Wk1, Wm1, wsb);
  edge_main<<<dim3(NBLK), dim3(256), 0, stream>>>(
      edge, nlen, nang, bq, bk2, bm2, bc, g_att, b_att, g_bn, b_bn,
      wsm, wsb, (float*)d_out);
}

// Round 11
// 277.812 us; speedup vs baseline: 3.5753x; 1.1131x over previous
//
#include <hip/hip_runtime.h>

#define E_TOTAL 50000
#define NTILES  3125      // E_TOTAL / 16, exact
#define NBLK    782       // ceil(NTILES / 4 waves)

typedef float f4  __attribute__((ext_vector_type(4)));
typedef short s8v __attribute__((ext_vector_type(8)));   // 8 bf16 bit-patterns (4 VGPRs)
typedef short s4v __attribute__((ext_vector_type(4)));   // 4 bf16 bit-patterns (2 VGPRs)

typedef __attribute__((address_space(3))) unsigned lds_u32;
typedef __attribute__((address_space(1))) const unsigned g_u32;

__device__ __forceinline__ short f2bf(float x){
  unsigned u = __builtin_bit_cast(unsigned, x);
  u += 0x7fffu + ((u >> 16) & 1u);           // RNE
  return (short)(u >> 16);
}
__device__ __forceinline__ float bf2f(short s){
  unsigned u = ((unsigned)(unsigned short)s) << 16;
  return __builtin_bit_cast(float, u);
}
__device__ __forceinline__ float sigm(float x){ return 1.f/(1.f + __expf(-x)); }

__device__ __forceinline__ s8v load_bfrag(const float* p){
  f4 a = *(const f4*)p;
  f4 b = *(const f4*)(p + 4);
  s8v r;
  r[0]=f2bf(a[0]); r[1]=f2bf(a[1]); r[2]=f2bf(a[2]); r[3]=f2bf(a[3]);
  r[4]=f2bf(b[0]); r[5]=f2bf(b[1]); r[6]=f2bf(b[2]); r[7]=f2bf(b[3]);
  return r;
}

// D[128 features x 16 edges] += A(from LDS) @ B ; 8 m-blocks x 4 k-chunks.
__device__ __forceinline__ void mm8l(f4* acc, const s8v* B, const s8v* A, int lane){
  #pragma unroll
  for (int mb = 0; mb < 8; ++mb){
    #pragma unroll
    for (int kk = 0; kk < 4; ++kk){
      s8v af = A[(mb*4 + kk)*64 + lane];
      acc[mb] = __builtin_amdgcn_mfma_f32_16x16x32_bf16(af, B[kk], acc[mb], 0, 0, 0);
    }
  }
}

// Cooperative 32KB matrix stage for 256 threads: 8 iters x 16B/thread.
// LDS dest is wave-uniform base + lane*16; pack layout is linear so this matches.
__device__ __forceinline__ void stage_mat(const short* __restrict__ src,
                                          short* dst, int wid, int lane){
  #pragma unroll
  for (int j = 0; j < 8; ++j){
    const short* gsrc = src + j*2048 + wid*512 + lane*8;   // bytes: j*4096 + wid*1024 + lane*16
    short* ldst = dst + j*2048 + wid*512;                  // wave-uniform
    __builtin_amdgcn_global_load_lds((g_u32*)(const void*)gsrc, (lds_u32*)(void*)ldst, 16, 0, 0);
  }
}

// ---------------------------------------------------------------------------
// Precompute: 14 fragment-ready bf16 A-matrices (A[m][k] = W[k][m], optionally
// W = X@Y fused product), packed so lane reads 16B contiguous per (mblk,kk).
//   mi 0 WqT(nat) | 1 GKT=Wk@Wk1a | 2 GMT=Wv@Wm1a | 3 GKaT=We@Wk1c | 4 GMaT=We@Wm1c
//   mi 5 Wk2T(dlay) | 6 Wm2T(dlay) | 7 WcT(dlay) | 8..10 GKeT[t] | 11..13 GMeT[t]
// ---------------------------------------------------------------------------
__global__ __launch_bounds__(256) void pack_weights(
    const float* __restrict__ Wq, const float* __restrict__ Wk, const float* __restrict__ Wv,
    const float* __restrict__ Wke, const float* __restrict__ Wve, const float* __restrict__ We,
    const float* __restrict__ Wc, const float* __restrict__ Wk1, const float* __restrict__ Wk2,
    const float* __restrict__ Wm1, const float* __restrict__ Wm2,
    short* __restrict__ wsm)
{
  int mi   = blockIdx.x >> 6;
  int elem = ((blockIdx.x & 63) << 8) + threadIdx.x;   // 0..16383
  int p  = elem & 7;
  int l  = (elem >> 3) & 63;
  int kk = (elem >> 9) & 3;
  int mb = elem >> 11;
  int gg = l >> 4;
  int m  = mb*16 + (l & 15);
  bool dlay = (mi == 5) || (mi == 6) || (mi == 7);
  int k = dlay ? (kk*32 + ((p < 4) ? (gg*4 + p) : (16 + gg*4 + (p - 4))))
               : (kk*32 + gg*8 + p);

  const float* X = nullptr; const float* Y = nullptr; const float* W = nullptr;
  switch (mi){
    case 0: W = Wq; break;
    case 1: X = Wk; Y = Wk1;            break;
    case 2: X = Wv; Y = Wm1;            break;
    case 3: X = We; Y = Wk1 + 256*128;  break;
    case 4: X = We; Y = Wm1 + 256*128;  break;
    case 5: W = Wk2; break;
    case 6: W = Wm2; break;
    case 7: W = Wc;  break;
    default:
      if (mi < 11){ X = Wke + (mi-8)*16384;  Y = Wk1 + 128*128; }
      else        { X = Wve + (mi-11)*16384; Y = Wm1 + 128*128; }
  }
  float v;
  if (W){
    v = W[k*128 + m];
  } else {
    v = 0.f;
    for (int j = 0; j < 128; ++j) v += X[k*128 + j] * Y[j*128 + m];
  }
  wsm[(size_t)mi*16384 + elem] = f2bf(v);
}

// biasK[t] = bk@Wk1a + bke[t]@Wk1b + bk1 ; biasM[t] = bv@Wm1a + bve[t]@Wm1b + bm1
__global__ __launch_bounds__(128) void make_biases(
    const float* __restrict__ bk,  const float* __restrict__ bke, const float* __restrict__ bk1,
    const float* __restrict__ bv,  const float* __restrict__ bve, const float* __restrict__ bm1,
    const float* __restrict__ Wk1, const float* __restrict__ Wm1,
    float* __restrict__ wsb)
{
  int b = blockIdx.x;          // 0..2 -> biasK[t], 3..5 -> biasM[t]
  int t = b % 3;
  bool isM = b >= 3;
  int o = threadIdx.x;
  const float* W  = isM ? Wm1 : Wk1;
  const float* b0 = isM ? bv  : bk;
  const float* be = (isM ? bve : bke) + t*128;
  const float* b1 = isM ? bm1 : bk1;
  float v = b1[o];
  for (int j = 0; j < 128; ++j)
    v += b0[j]*W[j*128 + o] + be[j]*W[(128 + j)*128 + o];
  wsb[b*128 + o] = v;
}

// ---------------------------------------------------------------------------
// Main fused kernel: 4 waves/block, 64 edges/block, 160 KiB LDS (1 block/CU).
// The 4 thrice-reused matrices (GKa,GMa,Wk2,Wm2) are LDS-PERSISTENT (staged
// once); only 10 single-use matrices stream through one 32KB buffer. Each
// streamed stage (except GK/GM/Wq/GKe0) is issued right after the previous
// stream matrix's last read and waited 2 compute-phases later -> only ~5 of
// 17 barriers carry exposed stage latency (vs 22/22 in the r2 structure).
// D[m=feature][n=edge]; lane holds edge (lane&15), features mb*16+(lane>>4)*4+r.
// ---------------------------------------------------------------------------
__global__ __launch_bounds__(256) void edge_main(
    const float* __restrict__ edge, const float* __restrict__ nlen, const float* __restrict__ nang,
    const float* __restrict__ bq,   const float* __restrict__ bk2,  const float* __restrict__ bm2,
    const float* __restrict__ bc,
    const float* __restrict__ g_att, const float* __restrict__ b_att,
    const float* __restrict__ g_bn,  const float* __restrict__ b_bn,
    const short* __restrict__ wsm,  const float* __restrict__ wsb,
    float* __restrict__ out)
{
  __shared__ short smem[81920];          // 160 KiB exactly
  short* PK_GKa = smem;                  // persistent 32KB each
  short* PK_GMa = smem + 16384;
  short* PK_Wk2 = smem + 32768;
  short* PK_Wm2 = smem + 49152;
  short* STRM   = smem + 65536;          // 32KB stream buffer

  const int lane = threadIdx.x & 63;
  const int wid  = threadIdx.x >> 6;
  int tile = blockIdx.x*4 + wid;
  if (tile > NTILES-1) tile = NTILES-1;  // tail waves redo last tile (uniform barriers)
  const int g  = lane >> 4;
  const int er = lane & 15;
  const size_t e = (size_t)tile*16 + er;
  const float* erow = edge + e*128;

  // ---- prologue: persistent set + first stream matrix (GK) + edge frags ----
  stage_mat(wsm + 3*16384, PK_GKa, wid, lane);
  stage_mat(wsm + 4*16384, PK_GMa, wid, lane);
  stage_mat(wsm + 5*16384, PK_Wk2, wid, lane);
  stage_mat(wsm + 6*16384, PK_Wm2, wid, lane);
  stage_mat(wsm + 1*16384, STRM,   wid, lane);     // GK

  s8v BE[4];
  #pragma unroll
  for (int kk = 0; kk < 4; ++kk) BE[kk] = load_bfrag(erow + kk*32 + g*8);

  f4 acc[8], gm[8];
  s4v qb[8], ekb[8], emb[8], gateb[8];
  s8v S[4], BL[4], BA[4];
  #pragma unroll
  for (int mb = 0; mb < 8; ++mb){ f4 z = {0.f,0.f,0.f,0.f}; gm[mb] = z; }

  __syncthreads();   // everything staged

  // p1: ek = BE @ GK
  #pragma unroll
  for (int mb = 0; mb < 8; ++mb){ f4 z = {0.f,0.f,0.f,0.f}; acc[mb] = z; }
  mm8l(acc, BE, (const s8v*)STRM, lane);
  #pragma unroll
  for (int mb = 0; mb < 8; ++mb){
    s4v t4; t4[0]=f2bf(acc[mb][0]); t4[1]=f2bf(acc[mb][1]); t4[2]=f2bf(acc[mb][2]); t4[3]=f2bf(acc[mb][3]);
    ekb[mb] = t4;
  }
  __syncthreads();                                  // done reading GK
  stage_mat(wsm + 2*16384, STRM, wid, lane);        // GM
  __syncthreads();                                  // exposed wait

  // p2: em = BE @ GM
  #pragma unroll
  for (int mb = 0; mb < 8; ++mb){ f4 z = {0.f,0.f,0.f,0.f}; acc[mb] = z; }
  mm8l(acc, BE, (const s8v*)STRM, lane);
  #pragma unroll
  for (int mb = 0; mb < 8; ++mb){
    s4v t4; t4[0]=f2bf(acc[mb][0]); t4[1]=f2bf(acc[mb][1]); t4[2]=f2bf(acc[mb][2]); t4[3]=f2bf(acc[mb][3]);
    emb[mb] = t4;
  }
  __syncthreads();                                  // done reading GM
  stage_mat(wsm + 0*16384, STRM, wid, lane);        // Wq
  __syncthreads();                                  // exposed wait

  // p3: q = bq + BE @ Wq ; load BL/BA(t=0)
  #pragma unroll
  for (int mb = 0; mb < 8; ++mb) acc[mb] = *(const f4*)(bq + mb*16 + g*4);
  mm8l(acc, BE, (const s8v*)STRM, lane);
  #pragma unroll
  for (int mb = 0; mb < 8; ++mb){
    s4v t4; t4[0]=f2bf(acc[mb][0]); t4[1]=f2bf(acc[mb][1]); t4[2]=f2bf(acc[mb][2]); t4[3]=f2bf(acc[mb][3]);
    qb[mb] = t4;
  }
  {
    const float* lrow = nlen + e*3*128;
    const float* arow = nang + e*3*128;
    #pragma unroll
    for (int kk = 0; kk < 4; ++kk){
      BL[kk] = load_bfrag(lrow + kk*32 + g*8);
      BA[kk] = load_bfrag(arow + kk*32 + g*8);
    }
  }
  __syncthreads();                                  // done reading Wq
  stage_mat(wsm + 8*16384, STRM, wid, lane);        // GKe0
  __syncthreads();                                  // exposed wait (drains BL/BA too)

  #pragma unroll 1
  for (int t = 0; t < 3; ++t){
    // pA: STRM = GKe[t] ; h = biasK[t] + ekb + BL@GKe[t]
    #pragma unroll
    for (int mb = 0; mb < 8; ++mb){
      f4 b = *(const f4*)(wsb + t*128 + mb*16 + g*4);
      #pragma unroll
      for (int r = 0; r < 4; ++r) b[r] += bf2f(ekb[mb][r]);
      acc[mb] = b;
    }
    mm8l(acc, BL, (const s8v*)STRM, lane);
    __syncthreads();                                // done reading GKe[t]
    stage_mat(wsm + (size_t)(11+t)*16384, STRM, wid, lane);   // GMe[t] (hidden)

    // pB (persistent GKa): h += BA@GKa ; silu -> S
    mm8l(acc, BA, (const s8v*)PK_GKa, lane);
    #pragma unroll
    for (int kk = 0; kk < 4; ++kk){
      #pragma unroll
      for (int p = 0; p < 4; ++p){
        float x0 = acc[2*kk][p];   S[kk][p]   = f2bf(x0 * sigm(x0));
        float x1 = acc[2*kk+1][p]; S[kk][4+p] = f2bf(x1 * sigm(x1));
      }
    }

    // pC (persistent Wk2): alpha = q .* (S@Wk2 + bk2)/sqrt(C) ; LN ; gate
    #pragma unroll
    for (int mb = 0; mb < 8; ++mb) acc[mb] = *(const f4*)(bk2 + mb*16 + g*4);
    mm8l(acc, S, (const s8v*)PK_Wk2, lane);
    {
      float sm = 0.f, ssq = 0.f;
      #pragma unroll
      for (int mb = 0; mb < 8; ++mb){
        #pragma unroll
        for (int r = 0; r < 4; ++r){
          float a = bf2f(qb[mb][r]) * acc[mb][r] * 0.08838834764831845f;
          acc[mb][r] = a; sm += a; ssq += a*a;
        }
      }
      sm  += __shfl_xor(sm, 16);  sm  += __shfl_xor(sm, 32);
      ssq += __shfl_xor(ssq, 16); ssq += __shfl_xor(ssq, 32);
      float mean = sm * (1.f/128.f);
      float rstd = rsqrtf(ssq * (1.f/128.f) - mean*mean + 1e-5f);
      #pragma unroll
      for (int mb = 0; mb < 8; ++mb){
        f4 ga = *(const f4*)(g_att + mb*16 + g*4);
        f4 bb = *(const f4*)(b_att + mb*16 + g*4);
        s4v t4;
        #pragma unroll
        for (int r = 0; r < 4; ++r)
          t4[r] = f2bf(sigm((acc[mb][r] - mean)*rstd*ga[r] + bb[r]));
        gateb[mb] = t4;
      }
    }
    __syncthreads();                                // GMe[t] ready (hidden under pB+pC)

    // pD: STRM = GMe[t] ; h = biasM[t] + emb + BL@GMe[t]
    #pragma unroll
    for (int mb = 0; mb < 8; ++mb){
      f4 b = *(const f4*)(wsb + 384 + t*128 + mb*16 + g*4);
      #pragma unroll
      for (int r = 0; r < 4; ++r) b[r] += bf2f(emb[mb][r]);
      acc[mb] = b;
    }
    mm8l(acc, BL, (const s8v*)STRM, lane);
    __syncthreads();                                // done reading GMe[t]
    stage_mat(t < 2 ? wsm + (size_t)(9+t)*16384 : wsm + (size_t)7*16384,
              STRM, wid, lane);                     // GKe[t+1] or Wc (hidden)
    if (t < 2){                                     // BL dead after pD
      const float* lrow = nlen + (e*3 + t + 1)*128;
      #pragma unroll
      for (int kk = 0; kk < 4; ++kk) BL[kk] = load_bfrag(lrow + kk*32 + g*8);
    }

    // pE (persistent GMa): h += BA@GMa ; silu -> S ; reload BA(t+1)
    mm8l(acc, BA, (const s8v*)PK_GMa, lane);
    #pragma unroll
    for (int kk = 0; kk < 4; ++kk){
      #pragma unroll
      for (int p = 0; p < 4; ++p){
        float x0 = acc[2*kk][p];   S[kk][p]   = f2bf(x0 * sigm(x0));
        float x1 = acc[2*kk+1][p]; S[kk][4+p] = f2bf(x1 * sigm(x1));
      }
    }
    if (t < 2){                                     // BA dead after pE's mm8l
      const float* arow = nang + (e*3 + t + 1)*128;
      #pragma unroll
      for (int kk = 0; kk < 4; ++kk) BA[kk] = load_bfrag(arow + kk*32 + g*8);
    }

    // pF (persistent Wm2): ma = S@Wm2 + bm2 ; gm += gate .* ma
    #pragma unroll
    for (int mb = 0; mb < 8; ++mb) acc[mb] = *(const f4*)(bm2 + mb*16 + g*4);
    mm8l(acc, S, (const s8v*)PK_Wm2, lane);
    #pragma unroll
    for (int mb = 0; mb < 8; ++mb){
      #pragma unroll
      for (int r = 0; r < 4; ++r) gm[mb][r] += acc[mb][r] * bf2f(gateb[mb][r]);
    }
    __syncthreads();                                // next stream matrix ready (hidden)
  }

  // epilogue: STRM = Wc ; o = gm@Wc + 3bc ; LN ; softplus(edge + .) ; store
  s8v GF[4];
  #pragma unroll
  for (int kk = 0; kk < 4; ++kk){
    #pragma unroll
    for (int p = 0; p < 4; ++p){
      GF[kk][p]   = f2bf(gm[2*kk][p]);
      GF[kk][4+p] = f2bf(gm[2*kk+1][p]);
    }
  }
  #pragma unroll
  for (int mb = 0; mb < 8; ++mb){
    f4 b = *(const f4*)(bc + mb*16 + g*4);
    #pragma unroll
    for (int r = 0; r < 4; ++r) b[r] *= 3.f;
    acc[mb] = b;
  }
  mm8l(acc, GF, (const s8v*)STRM, lane);

  float sm = 0.f, ssq = 0.f;
  #pragma unroll
  for (int mb = 0; mb < 8; ++mb){
    #pragma unroll
    for (int r = 0; r < 4; ++r){ sm += acc[mb][r]; ssq += acc[mb][r]*acc[mb][r]; }
  }
  sm  += __shfl_xor(sm, 16);  sm  += __shfl_xor(sm, 32);
  ssq += __shfl_xor(ssq, 16); ssq += __shfl_xor(ssq, 32);
  float mean = sm * (1.f/128.f);
  float rstd = rsqrtf(ssq * (1.f/128.f) - mean*mean + 1e-5f);

  #pragma unroll
  for (int mb = 0; mb < 8; ++mb){
    f4 ev  = *(const f4*)(erow + mb*16 + g*4);
    f4 gv  = *(const f4*)(g_bn + mb*16 + g*4);
    f4 bv2 = *(const f4*)(b_bn + mb*16 + g*4);
    f4 o;
    #pragma unroll
    for (int r = 0; r < 4; ++r){
      float x = ev[r] + (acc[mb][r] - mean)*rstd*gv[r] + bv2[r];
      o[r] = (x > 20.f) ? x : log1pf(__expf(x));
    }
    *(f4*)(out + e*128 + mb*16 + g*4) = o;
  }
}

extern "C" void kernel_launch(void* const* d_in, const int* in_sizes, int n_in,
                              void* d_out, int out_size, void* d_ws, size_t ws_size,
                              hipStream_t stream)
{
  const float* edge = (const float*)d_in[0];
  const float* nlen = (const float*)d_in[1];
  const float* nang = (const float*)d_in[2];
  const float* Wq  = (const float*)d_in[3];
  const float* bq  = (const float*)d_in[4];
  const float* Wk  = (const float*)d_in[5];
  const float* bk  = (const float*)d_in[6];
  const float* Wv  = (const float*)d_in[7];
  const float* bv  = (const float*)d_in[8];
  const float* Wke = (const float*)d_in[9];
  const float* bke = (const float*)d_in[10];
  const float* Wve = (const float*)d_in[11];
  const float* bve = (const float*)d_in[12];
  const float* We  = (const float*)d_in[13];
  const float* Wc  = (const float*)d_in[14];
  const float* bc  = (const float*)d_in[15];
  const float* Wk1 = (const float*)d_in[16];
  const float* bk1 = (const float*)d_in[17];
  const float* Wk2 = (const float*)d_in[18];
  const float* bk2 = (const float*)d_in[19];
  const float* Wm1 = (const float*)d_in[20];
  const float* bm1 = (const float*)d_in[21];
  const float* Wm2 = (const float*)d_in[22];
  const float* bm2 = (const float*)d_in[23];
  const float* g_att = (const float*)d_in[24];
  const float* b_att = (const float*)d_in[25];
  const float* g_bn  = (const float*)d_in[26];
  const float* b_bn  = (const float*)d_in[27];

  // ws layout: 14 packed bf16 matrices (16384 shorts each) + 6*128 f32 biases
  short* wsm = (short*)d_ws;
  float* wsb = (float*)((char*)d_ws + (size_t)14*16384*2);

  pack_weights<<<dim3(14*64), dim3(256), 0, stream>>>(
      Wq, Wk, Wv, Wke, Wve, We, Wc, Wk1, Wk2, Wm1, Wm2, wsm);
  make_biases<<<dim3(6), dim3(128), 0, stream>>>(
      bk, bke, bk1, bv, bve, bm1, Wk1, Wm1, wsb);
  edge_main<<<dim3(NBLK), dim3(256), 0, stream>>>(
      edge, nlen, nang, bq, bk2, bm2, bc, g_att, b_att, g_bn, b_bn,
      wsm, wsb, (float*)d_out);
}